// Round 9
// baseline (265.860 us; speedup 1.0000x reference)
//
#include <hip/hip_runtime.h>
#include <hip/hip_bf16.h>

// Self-attention fwd, fp16 MFMA, algebraic V/O fusion (out = P@(x@(Wo@Wv)^T)+c).
// gemm256: 256x256 tile, 8 waves, BK=64, 4 phases/K-tile split by (k-half,m-half),
//   128KB LDS double-slot, stage-to-other-slot, counted vmcnt(4) (never 0 mid-loop),
//   32 MFMA per barrier, rotation swizzle (R7-verified 0 conflicts).
// gemm128: proven triple-buffered loop (PV, Bvw).

typedef __attribute__((ext_vector_type(8))) _Float16 f16x8;
typedef __attribute__((ext_vector_type(4))) _Float16 f16x4;
typedef __attribute__((ext_vector_type(4))) float f32x4;

static __device__ __forceinline__ void gl_lds16(const void* g, void* s) {
  __builtin_amdgcn_global_load_lds(
      (const __attribute__((address_space(1))) void*)g,
      (__attribute__((address_space(3))) void*)s, 16, 0, 0);
}

__global__ __launch_bounds__(256) void cvt16(
    const float* __restrict__ x, _Float16* __restrict__ o, int n4) {
  int i = blockIdx.x * 256 + threadIdx.x;
  if (i >= n4) return;
  float4 v = reinterpret_cast<const float4*>(x)[i];
  f16x4 r = {(_Float16)v.x, (_Float16)v.y, (_Float16)v.z, (_Float16)v.w};
  reinterpret_cast<f16x4*>(o)[i] = r;
}

__global__ __launch_bounds__(256) void tr16(
    const float* __restrict__ Wv, _Float16* __restrict__ WvT) {
  __shared__ float t[64][65];
  const int tx = threadIdx.x & 63, ty = threadIdx.x >> 6;
  const int bx = blockIdx.x * 64, by = blockIdx.y * 64;
#pragma unroll
  for (int i = 0; i < 64; i += 4)
    t[ty + i][tx] = Wv[(long)(by + ty + i) * 1024 + bx + tx];
  __syncthreads();
#pragma unroll
  for (int i = 0; i < 64; i += 4)
    WvT[(long)(bx + ty + i) * 1024 + by + tx] = (_Float16)t[tx][ty + i];
}

__global__ __launch_bounds__(256) void ckern(
    const float* __restrict__ Wo, const float* __restrict__ bv,
    const float* __restrict__ bo, float* __restrict__ cpb) {
  const int n = blockIdx.x;
  const int tid = threadIdx.x;
  float s = 0.f;
  for (int d = tid; d < 1024; d += 256) s += Wo[(long)n * 1024 + d] * bv[d];
#pragma unroll
  for (int o = 32; o >= 1; o >>= 1) s += __shfl_xor(s, o);
  __shared__ float red[4];
  if ((tid & 63) == 0) red[tid >> 6] = s;
  __syncthreads();
  if (tid == 0) cpb[n] = red[0] + red[1] + red[2] + red[3] + bo[n];
}

__global__ __launch_bounds__(256) void pack_bias(
    const float* __restrict__ bq, const float* __restrict__ bk,
    float* __restrict__ o) {
  int i = blockIdx.x * 256 + threadIdx.x;
  if (i >= 3072) return;
  o[i] = (i < 1024) ? bq[i] : (i < 2048) ? bk[i - 1024] : 0.f;
}

// ======================= 256x256 4-phase GEMM =======================
// C = alpha * A @ B^T (+bias). A:[M][K], B:[N][K] fp16 row-major. K%64==0.
// EPI 1: fp16 Ch[bz*sC+row*N+col].  EPI 3: fused QKV' routing.
template <int EPI>
__global__ __launch_bounds__(512, 2) void gemm256(
    const _Float16* __restrict__ A, const _Float16* __restrict__ B,
    const float* __restrict__ bias, float* __restrict__ Cf,
    _Float16* __restrict__ Ch, _Float16* __restrict__ C2,
    _Float16* __restrict__ C3,
    int M, int N, int K, long sA, long sB, long sC, float alpha) {
  // [slot][A|B][khalf][256 rows * 32 cols, swizzled] = 128 KiB
  __shared__ _Float16 lds[2][2][2][8192];

  // XCD-chunked bijective remap (nwg % 8 == 0 for all launches)
  const unsigned nwg = gridDim.x * gridDim.y * gridDim.z;
  unsigned flat = (blockIdx.z * gridDim.y + blockIdx.y) * gridDim.x + blockIdx.x;
  flat = (flat & 7) * (nwg >> 3) + (flat >> 3);
  const unsigned bxi = flat % gridDim.x;
  const unsigned t2 = flat / gridDim.x;
  const unsigned byi = t2 % gridDim.y;
  const long bz = t2 / gridDim.y;

  const int tid = threadIdx.x;
  const int w = tid >> 6, lane = tid & 63;
  const int wr = w >> 2, wc = w & 3;   // 2M x 4N waves, per-wave 128x64
  const int lr = lane & 15, q = lane >> 4;
  const long row0 = (long)byi * 256;
  const long col0 = (long)bxi * 256;
  const int nt = K >> 6;

  const _Float16* pA = A + bz * sA;
  const _Float16* pB = B + bz * sB;

  f32x4 acc[8][4] = {};

  // staging: physical 16B slots tid and tid+512 of a [256 rows][4 slots] unit.
  // physical slot for logical (r,c4): 4r + ((c4 + (r>>1)) & 3)  -> conflict-free.
  const int r0 = tid >> 2, c0 = ((tid & 3) - (r0 >> 1)) & 3;
  const int s1i = tid + 512;
  const int r1 = s1i >> 2, c1 = ((s1i & 3) - (r1 >> 1)) & 3;

  auto stage = [&](int kt, int ab, int kh) {
    if (kt >= nt) return;
    const int sl = kt & 1;
    const _Float16* src = ab ? pB : pA;
    const long base = ab ? col0 : row0;
    const long gk = (long)kt * 64 + kh * 32;
    gl_lds16(src + (base + r0) * (long)K + gk + c0 * 8, &lds[sl][ab][kh][w << 9]);
    gl_lds16(src + (base + r1) * (long)K + gk + c1 * 8,
             &lds[sl][ab][kh][4096 + (w << 9)]);
  };
  auto rd = [&](int sl, int ab, int kh, int r) -> f16x8 {
    const int slot = (r << 2) + ((q + (r >> 1)) & 3);
    return *(const f16x8*)&lds[sl][ab][kh][slot << 3];
  };

  // prologue: tile 0 fully staged (4 units, 8 loads)
  stage(0, 0, 0); stage(0, 1, 0); stage(0, 0, 1); stage(0, 1, 1);

  f16x8 a0[4], a1[4], b0[4];
  for (int t = 0; t < nt; ++t) {
    const int sl = t & 1;
    // ---- entry: k0 units of tile t landed (k1 pair may remain in flight) ----
    asm volatile("s_waitcnt vmcnt(4)" ::: "memory");
    __builtin_amdgcn_s_barrier();
    __builtin_amdgcn_sched_barrier(0);
    // phase 1: (k0, m-half 0) + all B(k0); stage A(t+1,k0)
#pragma unroll
    for (int m = 0; m < 4; ++m) a0[m] = rd(sl, 0, 0, wr * 128 + m * 16 + lr);
#pragma unroll
    for (int n = 0; n < 4; ++n) b0[n] = rd(sl, 1, 0, wc * 64 + n * 16 + lr);
    stage(t + 1, 0, 0);
    __builtin_amdgcn_s_setprio(1);
#pragma unroll
    for (int m = 0; m < 4; ++m)
#pragma unroll
      for (int n = 0; n < 4; ++n)
        acc[m][n] = __builtin_amdgcn_mfma_f32_16x16x32_f16(a0[m], b0[n], acc[m][n], 0, 0, 0);
    __builtin_amdgcn_s_setprio(0);
    // phase 2: (k0, m-half 1); stage B(t+1,k0)
#pragma unroll
    for (int m = 0; m < 4; ++m) a1[m] = rd(sl, 0, 0, wr * 128 + 64 + m * 16 + lr);
    stage(t + 1, 1, 0);
    __builtin_amdgcn_s_setprio(1);
#pragma unroll
    for (int m = 0; m < 4; ++m)
#pragma unroll
      for (int n = 0; n < 4; ++n)
        acc[4 + m][n] = __builtin_amdgcn_mfma_f32_16x16x32_f16(a1[m], b0[n], acc[4 + m][n], 0, 0, 0);
    __builtin_amdgcn_s_setprio(0);
    // ---- mid: k1 units of tile t landed (t+1 k0 pair may remain in flight) ----
    if (t == nt - 1) asm volatile("s_waitcnt vmcnt(0)" ::: "memory");
    else             asm volatile("s_waitcnt vmcnt(4)" ::: "memory");
    __builtin_amdgcn_s_barrier();
    __builtin_amdgcn_sched_barrier(0);
    // phase 3: (k1, m-half 0) + all B(k1); stage A(t+1,k1)
#pragma unroll
    for (int m = 0; m < 4; ++m) a0[m] = rd(sl, 0, 1, wr * 128 + m * 16 + lr);
#pragma unroll
    for (int n = 0; n < 4; ++n) b0[n] = rd(sl, 1, 1, wc * 64 + n * 16 + lr);
    stage(t + 1, 0, 1);
    __builtin_amdgcn_s_setprio(1);
#pragma unroll
    for (int m = 0; m < 4; ++m)
#pragma unroll
      for (int n = 0; n < 4; ++n)
        acc[m][n] = __builtin_amdgcn_mfma_f32_16x16x32_f16(a0[m], b0[n], acc[m][n], 0, 0, 0);
    __builtin_amdgcn_s_setprio(0);
    // phase 4: (k1, m-half 1); stage B(t+1,k1)
#pragma unroll
    for (int m = 0; m < 4; ++m) a1[m] = rd(sl, 0, 1, wr * 128 + 64 + m * 16 + lr);
    stage(t + 1, 1, 1);
    __builtin_amdgcn_s_setprio(1);
#pragma unroll
    for (int m = 0; m < 4; ++m)
#pragma unroll
      for (int n = 0; n < 4; ++n)
        acc[4 + m][n] = __builtin_amdgcn_mfma_f32_16x16x32_f16(a1[m], b0[n], acc[4 + m][n], 0, 0, 0);
    __builtin_amdgcn_s_setprio(0);
  }

#pragma unroll
  for (int mi = 0; mi < 8; ++mi)
#pragma unroll
    for (int n = 0; n < 4; ++n)
#pragma unroll
      for (int r = 0; r < 4; ++r) {
        const long row = row0 + wr * 128 + mi * 16 + q * 4 + r;
        const long col = col0 + wc * 64 + n * 16 + lr;
        float v = acc[mi][n][r] * alpha;
        if (bias) v += bias[col];
        if (EPI == 1) {
          Ch[bz * sC + row * (long)N + col] = (_Float16)v;
        } else {  // EPI 3: fused QKV' routing, S=2048
          if (col < 1024) {
            Ch[row * 1024 + col] = (_Float16)v;
          } else if (col < 2048) {
            C2[row * 1024 + (col - 1024)] = (_Float16)v;
          } else {
            const long b2 = row >> 11;
            const long s2 = row & 2047;
            C3[(b2 * 1024 + (col - 2048)) * 2048 + s2] = (_Float16)v;
          }
        }
      }
}

// ======================= 128x128 GEMM (proven, PV + Bvw) =======================
template <int EPI, bool BB>
__global__ __launch_bounds__(256) void gemm128(
    const _Float16* __restrict__ A, const _Float16* __restrict__ B,
    const float* __restrict__ bias, float* __restrict__ Cf,
    _Float16* __restrict__ Ch,
    int M, int N, int K, long sA, long sB, long sC, float alpha) {
  __shared__ _Float16 lds[3][2][4096];

  const unsigned nwg = gridDim.x * gridDim.y * gridDim.z;
  unsigned flat = (blockIdx.z * gridDim.y + blockIdx.y) * gridDim.x + blockIdx.x;
  flat = (flat & 7) * (nwg >> 3) + (flat >> 3);
  const unsigned bxi = flat % gridDim.x;
  const unsigned t2 = flat / gridDim.x;
  const unsigned byi = t2 % gridDim.y;
  const long bz = t2 / gridDim.y;

  const int tid = threadIdx.x;
  const int w = tid >> 6, lane = tid & 63;
  const int wr = w >> 1, wc = w & 1;
  const int lr = lane & 15, q = lane >> 4;
  const long row0 = (long)byi * 128;
  const long col0 = (long)bxi * 128;
  const int nt = K >> 5;

  const _Float16* pA = A + bz * sA;
  const _Float16* pB = BB ? (B + (row0 >> 11) * sB) : (B + bz * sB);

  f32x4 acc[4][4] = {};

  const int r0 = tid >> 2, c0 = ((tid & 3) - (r0 >> 1)) & 3;
  const int s1 = tid + 256;
  const int r1 = s1 >> 2, c1 = ((s1 & 3) - (r1 >> 1)) & 3;

  auto stage = [&](int kt) {
    if (kt >= nt) return;
    const int bf = kt % 3;
    const long gk = (long)kt * 32;
#pragma unroll
    for (int ab = 0; ab < 2; ++ab) {
      const _Float16* src = ab ? pB : pA;
      const long base = ab ? col0 : row0;
      gl_lds16(src + (base + r0) * (long)K + gk + c0 * 8, &lds[bf][ab][w << 9]);
      gl_lds16(src + (base + r1) * (long)K + gk + c1 * 8, &lds[bf][ab][2048 + (w << 9)]);
    }
  };
  auto rd = [&](int bf, int ab, int r) -> f16x8 {
    const int slot = (r << 2) + ((q + (r >> 1)) & 3);
    return *(const f16x8*)&lds[bf][ab][slot << 3];
  };

  stage(0); stage(1);
  asm volatile("s_waitcnt vmcnt(4)" ::: "memory");
  __builtin_amdgcn_s_barrier();
  __builtin_amdgcn_sched_barrier(0);

  for (int kt = 0; kt < nt; ++kt) {
    const int bf = kt % 3;
    stage(kt + 2);
    f16x8 a[4], b[4];
#pragma unroll
    for (int m = 0; m < 4; ++m) a[m] = rd(bf, 0, wr * 64 + m * 16 + lr);
#pragma unroll
    for (int n = 0; n < 4; ++n) b[n] = rd(bf, 1, wc * 64 + n * 16 + lr);
#pragma unroll
    for (int m = 0; m < 4; ++m)
#pragma unroll
      for (int n = 0; n < 4; ++n)
        acc[m][n] = __builtin_amdgcn_mfma_f32_16x16x32_f16(a[m], b[n], acc[m][n], 0, 0, 0);
    if (kt < nt - 2) asm volatile("s_waitcnt vmcnt(4)" ::: "memory");
    else             asm volatile("s_waitcnt vmcnt(0)" ::: "memory");
    __builtin_amdgcn_s_barrier();
    __builtin_amdgcn_sched_barrier(0);
  }

#pragma unroll
  for (int m = 0; m < 4; ++m)
#pragma unroll
    for (int n = 0; n < 4; ++n)
#pragma unroll
      for (int r = 0; r < 4; ++r) {
        const long row = row0 + wr * 64 + m * 16 + q * 4 + r;
        const long col = col0 + wc * 64 + n * 16 + lr;
        float v = acc[m][n][r] * alpha;
        if (bias) v += bias[col];
        if (EPI == 0) Cf[bz * sC + row * (long)N + col] = v;
        else          Ch[bz * sC + row * (long)N + col] = (_Float16)v;
      }
}

// ------- row softmax: read fp16 scores, write fp32 probs + fp16 in place -------
__global__ __launch_bounds__(256) void softmax16(
    _Float16* __restrict__ Ph, float* __restrict__ attn) {
  const long row = blockIdx.x;
  _Float16* ph = Ph + row * 2048;
  float* ap = attn + row * 2048;
  const int tid = threadIdx.x;
  f16x8 v = reinterpret_cast<const f16x8*>(ph)[tid];
  float x[8];
#pragma unroll
  for (int j = 0; j < 8; ++j) x[j] = (float)v[j];
  float m = x[0];
#pragma unroll
  for (int j = 1; j < 8; ++j) m = fmaxf(m, x[j]);
#pragma unroll
  for (int o = 32; o >= 1; o >>= 1) m = fmaxf(m, __shfl_xor(m, o));
  __shared__ float red[4], red2[4];
  if ((tid & 63) == 0) red[tid >> 6] = m;
  __syncthreads();
  m = fmaxf(fmaxf(red[0], red[1]), fmaxf(red[2], red[3]));
  float s = 0.f;
#pragma unroll
  for (int j = 0; j < 8; ++j) { x[j] = expf(x[j] - m); s += x[j]; }
#pragma unroll
  for (int o = 32; o >= 1; o >>= 1) s += __shfl_xor(s, o);
  if ((tid & 63) == 0) red2[tid >> 6] = s;
  __syncthreads();
  s = red2[0] + red2[1] + red2[2] + red2[3];
  const float inv = 1.0f / s;
#pragma unroll
  for (int j = 0; j < 8; ++j) x[j] *= inv;
  reinterpret_cast<float4*>(ap)[tid * 2] = make_float4(x[0], x[1], x[2], x[3]);
  reinterpret_cast<float4*>(ap)[tid * 2 + 1] = make_float4(x[4], x[5], x[6], x[7]);
  f16x8 pv;
#pragma unroll
  for (int j = 0; j < 8; ++j) pv[j] = (_Float16)x[j];
  reinterpret_cast<f16x8*>(ph)[tid] = pv;
}

extern "C" void kernel_launch(void* const* d_in, const int* in_sizes, int n_in,
                              void* d_out, int out_size, void* d_ws, size_t ws_size,
                              hipStream_t stream) {
  const float* x  = (const float*)d_in[0];
  const float* Wk = (const float*)d_in[1];
  const float* bk = (const float*)d_in[2];
  const float* Wq = (const float*)d_in[3];
  const float* bq = (const float*)d_in[4];
  const float* Wv = (const float*)d_in[5];
  const float* bv = (const float*)d_in[6];
  const float* Wo = (const float*)d_in[7];
  const float* bo = (const float*)d_in[8];

  float* out  = (float*)d_out;                  // [4,2048,1024]
  float* attn = (float*)d_out + 8388608;        // [4,2048,2048]

  const size_t MB = 1024 * 1024;
  unsigned char* ws = (unsigned char*)d_ws;
  _Float16* xh   = (_Float16*)(ws + 0 * MB);    // [8192][1024]          16 MB
  _Float16* Wf   = (_Float16*)(ws + 16 * MB);   // [3072][1024] Wq|Wk|Bvw 6 MB
  _Float16* Woh  = (_Float16*)(ws + 22 * MB);   // Wo fp16                2 MB
  _Float16* WvT  = (_Float16*)(ws + 24 * MB);   // Wv^T fp16              2 MB
  float*    bqkv = (float*)   (ws + 26 * MB);   // [3072]
  float*    cpb  = (float*)   (ws + 26 * MB + 16384);  // [1024]
  _Float16* Qh   = (_Float16*)(ws + 27 * MB);   // [4][2048][1024]       16 MB
  _Float16* Kh   = (_Float16*)(ws + 43 * MB);   //                       16 MB
  _Float16* Vt   = (_Float16*)(ws + 59 * MB);   // V'^T [4][1024][2048]  16 MB
  _Float16* Ph   = (_Float16*)(ws + 75 * MB);   // [4][2048][2048]       32 MB

  dim3 blk(256);
  dim3 blk5(512);
  const _Float16* nullh = nullptr;

  hipLaunchKernelGGL(cvt16, dim3(8192), blk, 0, stream, x, xh, 2097152);
  hipLaunchKernelGGL(cvt16, dim3(1024), blk, 0, stream, Wq, Wf, 262144);
  hipLaunchKernelGGL(cvt16, dim3(1024), blk, 0, stream, Wk, Wf + 1048576, 262144);
  hipLaunchKernelGGL(cvt16, dim3(1024), blk, 0, stream, Wo, Woh, 262144);
  hipLaunchKernelGGL(tr16, dim3(16, 16), blk, 0, stream, Wv, WvT);
  hipLaunchKernelGGL(ckern, dim3(1024), blk, 0, stream, Wo, bv, bo, cpb);
  hipLaunchKernelGGL(pack_bias, dim3(12), blk, 0, stream, bq, bk, bqkv);

  // Bvw = Wo @ Wv  (fp16, third slot of Wf)
  hipLaunchKernelGGL((gemm128<1, false>), dim3(8, 8, 1), blk, 0, stream,
                     Woh, WvT, (const float*)nullptr, (float*)nullptr,
                     Wf + 2097152, 1024, 1024, 1024, 0L, 0L, 0L, 1.0f);
  // fused [Q|K|V'] = x @ [Wq|Wk|Bvw]^T + [bq|bk|0]   (V' written ^T per batch)
  hipLaunchKernelGGL((gemm256<3>), dim3(12, 32, 1), blk5, 0, stream,
                     xh, Wf, bqkv, (float*)nullptr, Qh, Kh, Vt,
                     8192, 3072, 1024, 0L, 0L, 0L, 1.0f);
  // scores (fp16) = scale * Q@K^T  (batched)
  hipLaunchKernelGGL((gemm256<1>), dim3(8, 8, 4), blk5, 0, stream,
                     Qh, Kh, (const float*)nullptr, (float*)nullptr, Ph,
                     (_Float16*)nullh, (_Float16*)nullh,
                     2048, 2048, 1024, 2097152L, 2097152L, 4194304L, 0.03125f);
  // softmax rows: attn fp32 + Ph fp16 (in place)
  hipLaunchKernelGGL(softmax16, dim3(8192), blk, 0, stream, Ph, attn);
  // out = P @ V' + cpb   (M flattened 8192; V' batch = row block >> 11)
  hipLaunchKernelGGL((gemm128<0, true>), dim3(8, 64, 1), blk, 0, stream,
                     Ph, Vt, cpb, out, (_Float16*)nullh,
                     8192, 1024, 2048, 0L, 2097152L, 0L, 1.0f);
}